// Round 10
// baseline (133.497 us; speedup 1.0000x reference)
//
#include <hip/hip_runtime.h>
#include <hip/hip_bf16.h>

typedef __bf16 bf16x8_t __attribute__((ext_vector_type(8)));
typedef float f32x4_t __attribute__((ext_vector_type(4)));

#define MFMA_BF16(a, b, c) __builtin_amdgcn_mfma_f32_16x16x32_bf16((a), (b), (c), 0, 0, 0)
#define VMW(N) asm volatile("s_waitcnt vmcnt(" #N ")" ::: "memory")
#define BARRIER() __builtin_amdgcn_s_barrier()

static constexpr int T_DIM = 512;
static constexpr int H_DIM = 7168;
static constexpr int F_DIM = 2048;

__device__ __forceinline__ ushort f2bf(float f) {
    return __builtin_bit_cast(ushort, __float2bfloat16(f));
}

// Async global->LDS, 16B per lane. Dest = wave-uniform base + lane*16 (HW rule).
__device__ __forceinline__ void gload_lds16(const void* g, void* l) {
    __builtin_amdgcn_global_load_lds(
        (const __attribute__((address_space(1))) unsigned int*)g,
        (__attribute__((address_space(3))) unsigned int*)(uintptr_t)l,
        16, 0, 0);
}

__global__ void cvt_x_kernel(const float* __restrict__ in, ushort* __restrict__ outp, int n4) {
    int i = blockIdx.x * 256 + threadIdx.x;
    if (i < n4) {
        float4 v = reinterpret_cast<const float4*>(in)[i];
        ushort4 o;
        o.x = f2bf(v.x); o.y = f2bf(v.y); o.z = f2bf(v.z); o.w = f2bf(v.w);
        reinterpret_cast<ushort4*>(outp)[i] = o;
    }
}

// ---------------- gate+up fused GEMM, combined N=4096, split-K ----------------
// BM=256, BN=256, BK=64. 512 thr = 8 waves (2m x 4n), wave tile 128x64.
// LDS 160KB: A single-buffer 32KB (refilled post-read-barrier each tile) +
// B fp32 double-buffer 128KB with counted vmcnt (VMW(8), never 0 in steady
// state). Scale-folding: BN=256 spans 2 scale blocks but each wave's 64-col
// span is inside one -> per-wave uniform srow (selected by wcn>>1).
__global__ __launch_bounds__(512, 2) void gate_up_kernel(
    const ushort* __restrict__ xb, const float* __restrict__ wg,
    const float* __restrict__ sg, const float* __restrict__ wu,
    const float* __restrict__ su, float* __restrict__ gp, int NTS)
{
    __shared__ ushort As[256 * 64];      // bf16, 32KB, single buffer
    __shared__ float  Bs[2][256 * 64];   // fp32, 2 x 64KB

    const int tid = threadIdx.x;
    const int lane = tid & 63;
    const int wid = tid >> 6;
    const int wr = wid >> 2, wcn = wid & 3;   // wave tile at (wr*128, wcn*64)
    const int bn = blockIdx.x, bm = blockIdx.y, bz = blockIdx.z;
    const int m0 = bm * 256;
    const int ks0 = bz * NTS, ks1 = ks0 + NTS;   // NTS even

    const float* __restrict__ Wb = (bn < 8) ? wg : wu;
    const float* __restrict__ srow = ((bn < 8) ? sg : su)
        + (size_t)((bn & 7) * 2 + (wcn >> 1)) * (H_DIM / 128);
    const int nb = (bn & 7) * 256;

    f32x4_t acc[8][4] = {};

    const int a_r = tid >> 3, a_cu = tid & 7;
    const int b_r = tid >> 4, b_c32 = (tid & 15) >> 1, b_half = tid & 1;

    auto STAGE_A = [&](int kt) {
        const int k0 = kt * 64;
        #pragma unroll
        for (int q = 0; q < 4; ++q) {            // A: 256x64 bf16, 4 chunks
            const int row = q * 64 + a_r;
            gload_lds16(&xb[(size_t)(m0 + row) * H_DIM + k0 + ((a_cu ^ (row & 7)) << 3)],
                        &As[(q * 8192 + tid * 16) >> 1]);
        }
    };
    auto STAGE_B = [&](int kt, int bb) {
        const int k0 = kt * 64;
        #pragma unroll
        for (int q = 0; q < 8; ++q) {            // B: 256x64 fp32, 8 chunks
            const int row = q * 32 + b_r;
            gload_lds16(&Wb[(size_t)(nb + row) * H_DIM + k0 + ((b_c32 ^ (row & 7)) << 3) + (b_half << 2)],
                        &Bs[bb][(q * 8192 + tid * 16) >> 2]);
        }
    };

    auto COMPUTE = [&](int bb) {
        #pragma unroll
        for (int ks = 0; ks < 2; ++ks) {
            const int kk = ks * 4 + (lane >> 4);
            bf16x8_t af[8];
            #pragma unroll
            for (int i = 0; i < 8; ++i) {
                const int row = wr * 128 + i * 16 + (lane & 15);
                af[i] = *reinterpret_cast<const bf16x8_t*>(&As[row * 64 + ((kk ^ (row & 7)) << 3)]);
            }
            #pragma unroll
            for (int j = 0; j < 4; ++j) {
                const int row = wcn * 64 + j * 16 + (lane & 15);
                const int u = kk ^ (row & 7);
                f32x4_t b0 = *reinterpret_cast<const f32x4_t*>(&Bs[bb][row * 64 + u * 8]);
                f32x4_t b1 = *reinterpret_cast<const f32x4_t*>(&Bs[bb][row * 64 + u * 8 + 4]);
                bf16x8_t bf;
                #pragma unroll
                for (int e = 0; e < 4; ++e) {    // pure casts -> cvt_pk pairs
                    bf[e]     = (__bf16)b0[e];
                    bf[e + 4] = (__bf16)b1[e];
                }
                #pragma unroll
                for (int i = 0; i < 8; ++i)
                    acc[i][j] = MFMA_BF16(af[i], bf, acc[i][j]);
            }
        }
    };

    float s_cur = srow[ks0 >> 1];

    STAGE_A(ks0);
    STAGE_B(ks0, 0);        // 12 outstanding
    STAGE_B(ks0 + 1, 1);    // 20 outstanding
    VMW(8);                 // A(ks0), B(ks0) done; B(ks0+1) in flight
    BARRIER();

    int bb = 0;
    for (int kt = ks0; kt < ks1; ++kt) {
        if (((kt & 1) == 0) && kt > ks0) {
            const float s_new = srow[kt >> 1];
            const float r = s_cur / s_new;
            #pragma unroll
            for (int i = 0; i < 8; ++i)
                #pragma unroll
                for (int j = 0; j < 4; ++j)
                    acc[i][j] *= r;
            s_cur = s_new;
        }
        COMPUTE(bb);
        BARRIER();                          // all waves done reading As + Bs[bb]
        if (kt + 1 < ks1) {
            STAGE_A(kt + 1);                // refill A (4 loads)
            if (kt + 2 < ks1) {
                STAGE_B(kt + 2, bb);        // 8 loads into freed B buffer
                VMW(8);                     // waits B(kt+1)+A(kt+1); B(kt+2) flies
            } else {
                VMW(0);                     // penultimate tile: drain
            }
            BARRIER();
        }
        bb ^= 1;
    }

    // fp32 partials: P[bz][T][4096], scaled by s_cur (last scale of this split)
    #pragma unroll
    for (int i = 0; i < 8; ++i)
        #pragma unroll
        for (int j = 0; j < 4; ++j)
            #pragma unroll
            for (int r = 0; r < 4; ++r) {
                const int m = m0 + wr * 128 + i * 16 + (lane >> 4) * 4 + r;
                const int nc = bn * 256 + wcn * 64 + j * 16 + (lane & 15);
                gp[(size_t)bz * T_DIM * 4096 + (size_t)m * 4096 + nc] = acc[i][j][r] * s_cur;
            }
}

// reduce split-K partials: h = silu(sum g) * (sum u), bf16. P cols [0,2048)=g, [2048,4096)=u
__global__ void h_reduce_kernel(const float* __restrict__ gp, ushort* __restrict__ hb,
                                int nsplit, int n4) {
    int i = blockIdx.x * 256 + threadIdx.x;
    if (i >= n4) return;
    const int m = i >> 9;
    const int c4 = i & 511;
    const size_t base = (size_t)m * 4096 + c4 * 4;
    const size_t stride = (size_t)T_DIM * 4096;
    float4 g = *reinterpret_cast<const float4*>(&gp[base]);
    float4 u = *reinterpret_cast<const float4*>(&gp[base + 2048]);
    for (int s = 1; s < nsplit; ++s) {
        float4 g2 = *reinterpret_cast<const float4*>(&gp[s * stride + base]);
        float4 u2 = *reinterpret_cast<const float4*>(&gp[s * stride + base + 2048]);
        g.x += g2.x; g.y += g2.y; g.z += g2.z; g.w += g2.w;
        u.x += u2.x; u.y += u2.y; u.z += u2.z; u.w += u2.w;
    }
    ushort4 o;
    o.x = f2bf(g.x / (1.0f + __expf(-g.x)) * u.x);
    o.y = f2bf(g.y / (1.0f + __expf(-g.y)) * u.y);
    o.z = f2bf(g.z / (1.0f + __expf(-g.z)) * u.z);
    o.w = f2bf(g.w / (1.0f + __expf(-g.w)) * u.w);
    reinterpret_cast<ushort4*>(hb)[i] = o;
}

// ---------------- down GEMM ----------------
// BM=256, BN=128, BK=64, K=2048. 512 thr = 8 waves (4m x 2n), wave 64x64.
// Full dbuf (128KB) + counted vmcnt (8 loads/tile). Optional split-K=2.
template <bool DIRECT>
__global__ __launch_bounds__(512, 2) void down_kernel(
    const ushort* __restrict__ hb, const float* __restrict__ wd,
    const float* __restrict__ sd, float* __restrict__ outp, int NTS)
{
    __shared__ ushort As[2][256 * 64];   // bf16, 2 x 32KB
    __shared__ float  Bs[2][128 * 64];   // fp32, 2 x 32KB

    const int tid = threadIdx.x;
    const int lane = tid & 63;
    const int wid = tid >> 6;
    const int wr = wid >> 1, wc = wid & 1;   // wave tile at (wr*64, wc*64)
    const int bn = blockIdx.x, bm = blockIdx.y, bz = blockIdx.z;
    const int m0 = bm * 256;
    const float* __restrict__ srow = sd + (size_t)bn * (F_DIM / 128);
    const int nb = bn * 128;
    const int ks0 = bz * NTS, ks1 = ks0 + NTS;

    f32x4_t acc[4][4] = {};

    const int a_r = tid >> 3, a_cu = tid & 7;
    const int b_r = tid >> 4, b_c32 = (tid & 15) >> 1, b_half = tid & 1;

    auto STAGE = [&](int kt, int bb) {
        const int k0 = kt * 64;
        #pragma unroll
        for (int q = 0; q < 4; ++q) {            // A: 256x64 bf16, 4 chunks
            const int row = q * 64 + a_r;
            gload_lds16(&hb[(size_t)(m0 + row) * F_DIM + k0 + ((a_cu ^ (row & 7)) << 3)],
                        &As[bb][(q * 8192 + tid * 16) >> 1]);
        }
        #pragma unroll
        for (int q = 0; q < 4; ++q) {            // B: 128x64 fp32, 4 chunks
            const int row = q * 32 + b_r;
            gload_lds16(&wd[(size_t)(nb + row) * F_DIM + k0 + ((b_c32 ^ (row & 7)) << 3) + (b_half << 2)],
                        &Bs[bb][(q * 8192 + tid * 16) >> 2]);
        }
    };

    auto COMPUTE = [&](int bb) {
        #pragma unroll
        for (int ks = 0; ks < 2; ++ks) {
            const int kk = ks * 4 + (lane >> 4);
            bf16x8_t af[4];
            #pragma unroll
            for (int i = 0; i < 4; ++i) {
                const int row = wr * 64 + i * 16 + (lane & 15);
                af[i] = *reinterpret_cast<const bf16x8_t*>(&As[bb][row * 64 + ((kk ^ (row & 7)) << 3)]);
            }
            #pragma unroll
            for (int j = 0; j < 4; ++j) {
                const int row = wc * 64 + j * 16 + (lane & 15);
                const int u = kk ^ (row & 7);
                f32x4_t b0 = *reinterpret_cast<const f32x4_t*>(&Bs[bb][row * 64 + u * 8]);
                f32x4_t b1 = *reinterpret_cast<const f32x4_t*>(&Bs[bb][row * 64 + u * 8 + 4]);
                bf16x8_t bf;
                #pragma unroll
                for (int e = 0; e < 4; ++e) {
                    bf[e]     = (__bf16)b0[e];
                    bf[e + 4] = (__bf16)b1[e];
                }
                #pragma unroll
                for (int i = 0; i < 4; ++i)
                    acc[i][j] = MFMA_BF16(af[i], bf, acc[i][j]);
            }
        }
    };

    float s_cur = srow[ks0 >> 1];

    STAGE(ks0, 0);        // 8 outstanding
    STAGE(ks0 + 1, 1);    // 16 outstanding
    int bb = 0;
    for (int kt = ks0; kt < ks1; ++kt) {
        if (kt + 1 < ks1) { VMW(8); }
        else              { VMW(0); }
        BARRIER();
        if (((kt & 1) == 0) && kt > ks0) {
            const float s_new = srow[kt >> 1];
            const float r = s_cur / s_new;
            #pragma unroll
            for (int i = 0; i < 4; ++i)
                #pragma unroll
                for (int j = 0; j < 4; ++j)
                    acc[i][j] *= r;
            s_cur = s_new;
        }
        COMPUTE(bb);
        if (kt + 2 < ks1) {
            BARRIER();
            STAGE(kt + 2, bb);
        }
        bb ^= 1;
    }

    #pragma unroll
    for (int i = 0; i < 4; ++i)
        #pragma unroll
        for (int j = 0; j < 4; ++j)
            #pragma unroll
            for (int r = 0; r < 4; ++r) {
                const int m = m0 + wr * 64 + i * 16 + (lane >> 4) * 4 + r;
                const int nc = nb + wc * 64 + j * 16 + (lane & 15);
                const float v = acc[i][j][r] * s_cur;
                if (DIRECT)
                    outp[(size_t)m * H_DIM + nc] = v;
                else
                    outp[(size_t)bz * T_DIM * H_DIM + (size_t)m * H_DIM + nc] = v;
            }
}

__global__ void d_reduce_kernel(const float* __restrict__ dp, float* __restrict__ out, int n4) {
    int i = blockIdx.x * 256 + threadIdx.x;
    if (i >= n4) return;
    const size_t stride4 = (size_t)T_DIM * H_DIM / 4;
    float4 a = reinterpret_cast<const float4*>(dp)[i];
    float4 b = reinterpret_cast<const float4*>(dp)[i + stride4];
    a.x += b.x; a.y += b.y; a.z += b.z; a.w += b.w;
    reinterpret_cast<float4*>(out)[i] = a;
}

extern "C" void kernel_launch(void* const* d_in, const int* in_sizes, int n_in,
                              void* d_out, int out_size, void* d_ws, size_t ws_size,
                              hipStream_t stream) {
    const float* x  = (const float*)d_in[0];
    const float* wg = (const float*)d_in[1];
    const float* sg = (const float*)d_in[2];
    const float* wu = (const float*)d_in[3];
    const float* su = (const float*)d_in[4];
    const float* wd = (const float*)d_in[5];
    const float* sd = (const float*)d_in[6];
    float* out = (float*)d_out;

    ushort* xb = (ushort*)d_ws;                       // 7.34 MB
    ushort* hb = xb + (size_t)T_DIM * H_DIM;          // 2.10 MB
    float*  gp = (float*)(hb + (size_t)T_DIM * F_DIM);

    const size_t base_b = (size_t)T_DIM * H_DIM * 2 + (size_t)T_DIM * F_DIM * 2;
    const size_t split_b = (size_t)T_DIM * 4096 * 4;  // combined g|u fp32 per split

    int nsplit = 1;
    if (ws_size >= base_b + 4 * split_b) nsplit = 4;
    else if (ws_size >= base_b + 2 * split_b) nsplit = 2;

    const int n4x = T_DIM * H_DIM / 4;
    cvt_x_kernel<<<n4x / 256, 256, 0, stream>>>(x, xb, n4x);

    // grid (16, 2, nsplit): linear id % 8 == bn % 8 -> weight-sharing blocks on one XCD
    gate_up_kernel<<<dim3(16, T_DIM / 256, nsplit), 512, 0, stream>>>(
        xb, wg, sg, wu, su, gp, (H_DIM / 64) / nsplit);

    const int n4h = T_DIM * F_DIM / 4;
    h_reduce_kernel<<<n4h / 256, 256, 0, stream>>>(gp, hb, nsplit, n4h);

    // down: split-K=2 reusing gp (free after h_reduce) when it's big enough.
    const bool dsplit = (size_t)nsplit * split_b >= (size_t)2 * T_DIM * H_DIM * 4;
    if (dsplit) {
        float* dp = gp;
        down_kernel<false><<<dim3(H_DIM / 128, T_DIM / 256, 2), 512, 0, stream>>>(
            hb, wd, sd, dp, (F_DIM / 64) / 2);
        const int n4d = T_DIM * H_DIM / 4;
        d_reduce_kernel<<<n4d / 256, 256, 0, stream>>>(dp, out, n4d);
    } else {
        down_kernel<true><<<dim3(H_DIM / 128, T_DIM / 256, 1), 512, 0, stream>>>(
            hb, wd, sd, out, F_DIM / 64);
    }
}

// Round 11
// 99.821 us; speedup vs baseline: 1.3374x; 1.3374x over previous
//
#include <hip/hip_runtime.h>
#include <hip/hip_bf16.h>

typedef __bf16 bf16x8_t __attribute__((ext_vector_type(8)));
typedef float f32x4_t __attribute__((ext_vector_type(4)));

#define MFMA_BF16(a, b, c) __builtin_amdgcn_mfma_f32_16x16x32_bf16((a), (b), (c), 0, 0, 0)
#define VMW(N) asm volatile("s_waitcnt vmcnt(" #N ")" ::: "memory")
#define BARRIER() __builtin_amdgcn_s_barrier()

static constexpr int T_DIM = 512;
static constexpr int H_DIM = 7168;
static constexpr int F_DIM = 2048;

__device__ __forceinline__ ushort f2bf(float f) {
    return __builtin_bit_cast(ushort, __float2bfloat16(f));
}

// Async global->LDS, 16B per lane. Dest = wave-uniform base + lane*16 (HW rule).
__device__ __forceinline__ void gload_lds16(const void* g, void* l) {
    __builtin_amdgcn_global_load_lds(
        (const __attribute__((address_space(1))) unsigned int*)g,
        (__attribute__((address_space(3))) unsigned int*)(uintptr_t)l,
        16, 0, 0);
}

__global__ void cvt_x_kernel(const float* __restrict__ in, ushort* __restrict__ outp, int n4) {
    int i = blockIdx.x * 256 + threadIdx.x;
    if (i < n4) {
        float4 v = reinterpret_cast<const float4*>(in)[i];
        ushort4 o;
        o.x = f2bf(v.x); o.y = f2bf(v.y); o.z = f2bf(v.z); o.w = f2bf(v.w);
        reinterpret_cast<ushort4*>(outp)[i] = o;
    }
}

// ---------------- gate+up fused GEMM, combined N=4096, split-K ----------------
// BM=256, BN=128, BK=64 (r9 structure: full dbuf A+B, counted vmcnt, 2-deep).
// NEW: 1D grid, XCD-pinned decode. XCD = id%8 (dispatch round-robin). All 32
// bn-blocks with the same (bm,bz) land on one XCD -> their shared x k-slice
// (32KB/tile-step) is L2-resident: x fabric traffic 235MB -> ~10MB.
__global__ __launch_bounds__(512, 2) void gate_up_kernel(
    const ushort* __restrict__ xb, const float* __restrict__ wg,
    const float* __restrict__ sg, const float* __restrict__ wu,
    const float* __restrict__ su, float* __restrict__ gp, int NTS, int nsplit)
{
    __shared__ ushort As[2][256 * 64];   // bf16, 2 x 32KB
    __shared__ float  Bs[2][128 * 64];   // fp32, 2 x 32KB

    const int tid = threadIdx.x;
    const int lane = tid & 63;
    const int wid = tid >> 6;
    const int wr = wid >> 1, wc = wid & 1;   // wave tile at (wr*64, wc*64)

    // XCD-pinned decode: combos = 2*nsplit; same (bm,bz) -> same id%combos -> same XCD(s)
    const int id = blockIdx.x;
    const int combos = nsplit << 1;
    const int c = id & (combos - 1);         // combos is a power of 2
    const int bn = id >> (31 - __builtin_clz(combos));
    const int bm = c & 1, bz = c >> 1;

    const int m0 = bm * 256;
    const int ks0 = bz * NTS, ks1 = ks0 + NTS;   // NTS even

    const float* __restrict__ Wb = (bn < 16) ? wg : wu;
    const float* __restrict__ srow = ((bn < 16) ? sg : su) + (size_t)(bn & 15) * (H_DIM / 128);
    const int nb = (bn & 15) * 128;

    f32x4_t acc[4][4] = {};

    const int a_r = tid >> 3, a_cu = tid & 7;
    const int b_r = tid >> 4, b_c32 = (tid & 15) >> 1, b_half = tid & 1;

    auto STAGE = [&](int kt, int bb) {
        const int k0 = kt * 64;
        #pragma unroll
        for (int q = 0; q < 4; ++q) {            // A: 256x64 bf16, 4 chunks
            const int row = q * 64 + a_r;
            gload_lds16(&xb[(size_t)(m0 + row) * H_DIM + k0 + ((a_cu ^ (row & 7)) << 3)],
                        &As[bb][(q * 8192 + tid * 16) >> 1]);
        }
        #pragma unroll
        for (int q = 0; q < 4; ++q) {            // B: 128x64 fp32, 4 chunks
            const int row = q * 32 + b_r;
            gload_lds16(&Wb[(size_t)(nb + row) * H_DIM + k0 + ((b_c32 ^ (row & 7)) << 3) + (b_half << 2)],
                        &Bs[bb][(q * 8192 + tid * 16) >> 2]);
        }
    };

    auto COMPUTE = [&](int bb) {
        #pragma unroll
        for (int ks = 0; ks < 2; ++ks) {
            const int kk = ks * 4 + (lane >> 4);
            bf16x8_t af[4];
            #pragma unroll
            for (int i = 0; i < 4; ++i) {
                const int row = wr * 64 + i * 16 + (lane & 15);
                af[i] = *reinterpret_cast<const bf16x8_t*>(&As[bb][row * 64 + ((kk ^ (row & 7)) << 3)]);
            }
            #pragma unroll
            for (int j = 0; j < 4; ++j) {
                const int row = wc * 64 + j * 16 + (lane & 15);
                const int u = kk ^ (row & 7);
                f32x4_t b0 = *reinterpret_cast<const f32x4_t*>(&Bs[bb][row * 64 + u * 8]);
                f32x4_t b1 = *reinterpret_cast<const f32x4_t*>(&Bs[bb][row * 64 + u * 8 + 4]);
                bf16x8_t bf;
                #pragma unroll
                for (int e = 0; e < 4; ++e) {    // pure casts -> cvt_pk pairs
                    bf[e]     = (__bf16)b0[e];
                    bf[e + 4] = (__bf16)b1[e];
                }
                #pragma unroll
                for (int i = 0; i < 4; ++i)
                    acc[i][j] = MFMA_BF16(af[i], bf, acc[i][j]);
            }
        }
    };

    float s_cur = srow[ks0 >> 1];

    STAGE(ks0, 0);        // 8 outstanding
    STAGE(ks0 + 1, 1);    // 16 outstanding
    int bb = 0;
    for (int kt = ks0; kt < ks1; ++kt) {
        if (kt + 1 < ks1) { VMW(8); }   // tile kt complete; kt+1 stays in flight
        else              { VMW(0); }
        BARRIER();
        if (((kt & 1) == 0) && kt > ks0) {
            const float s_new = srow[kt >> 1];
            const float r = s_cur / s_new;
            #pragma unroll
            for (int i = 0; i < 4; ++i)
                #pragma unroll
                for (int j = 0; j < 4; ++j)
                    acc[i][j] *= r;
            s_cur = s_new;
        }
        COMPUTE(bb);
        if (kt + 2 < ks1) {
            BARRIER();                   // all waves done reading buf bb
            STAGE(kt + 2, bb);           // refill it; loads fly across barriers
        }
        bb ^= 1;
    }

    // fp32 partials: P[bz][T][4096], scaled by s_cur (last scale of this split)
    #pragma unroll
    for (int i = 0; i < 4; ++i)
        #pragma unroll
        for (int j = 0; j < 4; ++j)
            #pragma unroll
            for (int r = 0; r < 4; ++r) {
                const int m = m0 + wr * 64 + i * 16 + (lane >> 4) * 4 + r;
                const int nc = bn * 128 + wc * 64 + j * 16 + (lane & 15);
                gp[(size_t)bz * T_DIM * 4096 + (size_t)m * 4096 + nc] = acc[i][j][r] * s_cur;
            }
}

// reduce split-K partials: h = silu(sum g) * (sum u), bf16. P cols [0,2048)=g, [2048,4096)=u
__global__ void h_reduce_kernel(const float* __restrict__ gp, ushort* __restrict__ hb,
                                int nsplit, int n4) {
    int i = blockIdx.x * 256 + threadIdx.x;
    if (i >= n4) return;
    const int m = i >> 9;
    const int c4 = i & 511;
    const size_t base = (size_t)m * 4096 + c4 * 4;
    const size_t stride = (size_t)T_DIM * 4096;
    float4 g = *reinterpret_cast<const float4*>(&gp[base]);
    float4 u = *reinterpret_cast<const float4*>(&gp[base + 2048]);
    for (int s = 1; s < nsplit; ++s) {
        float4 g2 = *reinterpret_cast<const float4*>(&gp[s * stride + base]);
        float4 u2 = *reinterpret_cast<const float4*>(&gp[s * stride + base + 2048]);
        g.x += g2.x; g.y += g2.y; g.z += g2.z; g.w += g2.w;
        u.x += u2.x; u.y += u2.y; u.z += u2.z; u.w += u2.w;
    }
    ushort4 o;
    o.x = f2bf(g.x / (1.0f + __expf(-g.x)) * u.x);
    o.y = f2bf(g.y / (1.0f + __expf(-g.y)) * u.y);
    o.z = f2bf(g.z / (1.0f + __expf(-g.z)) * u.z);
    o.w = f2bf(g.w / (1.0f + __expf(-g.w)) * u.w);
    reinterpret_cast<ushort4*>(hb)[i] = o;
}

// ---------------- down GEMM ----------------
// BM=256, BN=128, BK=64, K=2048. r9 structure + XCD-pinned decode: same
// (bm,bz) -> same id%combos -> same XCD pair, so the shared hb k-slice
// (0.5MB) is L2-resident: hb fabric traffic 117MB -> ~5MB.
template <bool DIRECT>
__global__ __launch_bounds__(512, 2) void down_kernel(
    const ushort* __restrict__ hb, const float* __restrict__ wd,
    const float* __restrict__ sd, float* __restrict__ outp, int NTS, int nsplit)
{
    __shared__ ushort As[2][256 * 64];   // bf16, 2 x 32KB
    __shared__ float  Bs[2][128 * 64];   // fp32, 2 x 32KB

    const int tid = threadIdx.x;
    const int lane = tid & 63;
    const int wid = tid >> 6;
    const int wr = wid >> 1, wc = wid & 1;   // wave tile at (wr*64, wc*64)

    const int id = blockIdx.x;
    const int combos = nsplit << 1;
    const int c = id & (combos - 1);
    const int bn = id >> (31 - __builtin_clz(combos));
    const int bm = c & 1, bz = c >> 1;

    const int m0 = bm * 256;
    const float* __restrict__ srow = sd + (size_t)bn * (F_DIM / 128);
    const int nb = bn * 128;
    const int ks0 = bz * NTS, ks1 = ks0 + NTS;

    f32x4_t acc[4][4] = {};

    const int a_r = tid >> 3, a_cu = tid & 7;
    const int b_r = tid >> 4, b_c32 = (tid & 15) >> 1, b_half = tid & 1;

    auto STAGE = [&](int kt, int bb) {
        const int k0 = kt * 64;
        #pragma unroll
        for (int q = 0; q < 4; ++q) {            // A: 256x64 bf16, 4 chunks
            const int row = q * 64 + a_r;
            gload_lds16(&hb[(size_t)(m0 + row) * F_DIM + k0 + ((a_cu ^ (row & 7)) << 3)],
                        &As[bb][(q * 8192 + tid * 16) >> 1]);
        }
        #pragma unroll
        for (int q = 0; q < 4; ++q) {            // B: 128x64 fp32, 4 chunks
            const int row = q * 32 + b_r;
            gload_lds16(&wd[(size_t)(nb + row) * F_DIM + k0 + ((b_c32 ^ (row & 7)) << 3) + (b_half << 2)],
                        &Bs[bb][(q * 8192 + tid * 16) >> 2]);
        }
    };

    auto COMPUTE = [&](int bb) {
        #pragma unroll
        for (int ks = 0; ks < 2; ++ks) {
            const int kk = ks * 4 + (lane >> 4);
            bf16x8_t af[4];
            #pragma unroll
            for (int i = 0; i < 4; ++i) {
                const int row = wr * 64 + i * 16 + (lane & 15);
                af[i] = *reinterpret_cast<const bf16x8_t*>(&As[bb][row * 64 + ((kk ^ (row & 7)) << 3)]);
            }
            #pragma unroll
            for (int j = 0; j < 4; ++j) {
                const int row = wc * 64 + j * 16 + (lane & 15);
                const int u = kk ^ (row & 7);
                f32x4_t b0 = *reinterpret_cast<const f32x4_t*>(&Bs[bb][row * 64 + u * 8]);
                f32x4_t b1 = *reinterpret_cast<const f32x4_t*>(&Bs[bb][row * 64 + u * 8 + 4]);
                bf16x8_t bf;
                #pragma unroll
                for (int e = 0; e < 4; ++e) {
                    bf[e]     = (__bf16)b0[e];
                    bf[e + 4] = (__bf16)b1[e];
                }
                #pragma unroll
                for (int i = 0; i < 4; ++i)
                    acc[i][j] = MFMA_BF16(af[i], bf, acc[i][j]);
            }
        }
    };

    float s_cur = srow[ks0 >> 1];

    STAGE(ks0, 0);        // 8 outstanding
    STAGE(ks0 + 1, 1);    // 16 outstanding
    int bb = 0;
    for (int kt = ks0; kt < ks1; ++kt) {
        if (kt + 1 < ks1) { VMW(8); }
        else              { VMW(0); }
        BARRIER();
        if (((kt & 1) == 0) && kt > ks0) {
            const float s_new = srow[kt >> 1];
            const float r = s_cur / s_new;
            #pragma unroll
            for (int i = 0; i < 4; ++i)
                #pragma unroll
                for (int j = 0; j < 4; ++j)
                    acc[i][j] *= r;
            s_cur = s_new;
        }
        COMPUTE(bb);
        if (kt + 2 < ks1) {
            BARRIER();
            STAGE(kt + 2, bb);
        }
        bb ^= 1;
    }

    #pragma unroll
    for (int i = 0; i < 4; ++i)
        #pragma unroll
        for (int j = 0; j < 4; ++j)
            #pragma unroll
            for (int r = 0; r < 4; ++r) {
                const int m = m0 + wr * 64 + i * 16 + (lane >> 4) * 4 + r;
                const int nc = nb + wc * 64 + j * 16 + (lane & 15);
                const float v = acc[i][j][r] * s_cur;
                if (DIRECT)
                    outp[(size_t)m * H_DIM + nc] = v;
                else
                    outp[(size_t)bz * T_DIM * H_DIM + (size_t)m * H_DIM + nc] = v;
            }
}

__global__ void d_reduce_kernel(const float* __restrict__ dp, float* __restrict__ out, int n4) {
    int i = blockIdx.x * 256 + threadIdx.x;
    if (i >= n4) return;
    const size_t stride4 = (size_t)T_DIM * H_DIM / 4;
    float4 a = reinterpret_cast<const float4*>(dp)[i];
    float4 b = reinterpret_cast<const float4*>(dp)[i + stride4];
    a.x += b.x; a.y += b.y; a.z += b.z; a.w += b.w;
    reinterpret_cast<float4*>(out)[i] = a;
}

extern "C" void kernel_launch(void* const* d_in, const int* in_sizes, int n_in,
                              void* d_out, int out_size, void* d_ws, size_t ws_size,
                              hipStream_t stream) {
    const float* x  = (const float*)d_in[0];
    const float* wg = (const float*)d_in[1];
    const float* sg = (const float*)d_in[2];
    const float* wu = (const float*)d_in[3];
    const float* su = (const float*)d_in[4];
    const float* wd = (const float*)d_in[5];
    const float* sd = (const float*)d_in[6];
    float* out = (float*)d_out;

    ushort* xb = (ushort*)d_ws;                       // 7.34 MB
    ushort* hb = xb + (size_t)T_DIM * H_DIM;          // 2.10 MB
    float*  gp = (float*)(hb + (size_t)T_DIM * F_DIM);

    const size_t base_b = (size_t)T_DIM * H_DIM * 2 + (size_t)T_DIM * F_DIM * 2;
    const size_t split_b = (size_t)T_DIM * 4096 * 4;  // combined g|u fp32 per split

    int nsplit = 1;
    if (ws_size >= base_b + 4 * split_b) nsplit = 4;
    else if (ws_size >= base_b + 2 * split_b) nsplit = 2;

    const int n4x = T_DIM * H_DIM / 4;
    cvt_x_kernel<<<n4x / 256, 256, 0, stream>>>(x, xb, n4x);

    // 1D grid, XCD-pinned: id%(2*nsplit) selects (bm,bz); all bn-blocks of one
    // (bm,bz) share an XCD -> shared x k-slice is L2-resident.
    gate_up_kernel<<<32 * 2 * nsplit, 512, 0, stream>>>(
        xb, wg, sg, wu, su, gp, (H_DIM / 64) / nsplit, nsplit);

    const int n4h = T_DIM * F_DIM / 4;
    h_reduce_kernel<<<n4h / 256, 256, 0, stream>>>(gp, hb, nsplit, n4h);

    // down: split-K=2 reusing gp (free after h_reduce) when it's big enough.
    const bool dsplit = (size_t)nsplit * split_b >= (size_t)2 * T_DIM * H_DIM * 4;
    if (dsplit) {
        float* dp = gp;
        down_kernel<false><<<56 * 2 * 2, 512, 0, stream>>>(
            hb, wd, sd, dp, (F_DIM / 64) / 2, 2);
        const int n4d = T_DIM * H_DIM / 4;
        d_reduce_kernel<<<n4d / 256, 256, 0, stream>>>(dp, out, n4d);
    } else {
        down_kernel<true><<<56 * 2 * 1, 512, 0, stream>>>(
            hb, wd, sd, out, F_DIM / 64, 1);
    }
}